// Round 6
// baseline (111.366 us; speedup 1.0000x reference)
//
#include <hip/hip_runtime.h>

// Inverse Haar wavelet 2D (fp32):
//   x:       [B=16, 4C=256, H=128, W=128]
//   filters: [4C,1,2,2] viewed as [C,4,2,2]
//   out:     [B, C=64, 256, 256]
// out[b][c][2h+p][2w+q] = sum_k x[b][4c+k][h][w] * f[c][k][p][q]
//
// v3: sequential-stream walk. Each block owns one (b,c); its 4 waves each
// own an h-quarter (32 rows) and walk h innermost. Per iteration a wave
// reads one full 512B row from each of 4 subband planes (streams advance
// sequentially by 512B) and writes two full 1KB output rows (streams
// advance sequentially by 2KB). 1024 blocks = 4/CU, 16 waves/CU.

typedef float f32x2 __attribute__((ext_vector_type(2)));
typedef float f32x4 __attribute__((ext_vector_type(4)));

#define BB 16
#define CC 64
#define HH 128
#define WW 128
#define W2 (WW / 2)            // 64 column-pairs -> one wave spans a row
#define HBLK 4                 // h-quarters (one per wave in the block)
#define HPB (HH / HBLK)        // 32 rows walked per wave
#define NTHREADS (BB * CC * HBLK * W2)   // 262144 -> 1024 blocks

__global__ __launch_bounds__(256) void ihaar2d_kernel(
    const float* __restrict__ x,
    const float* __restrict__ filt,
    float* __restrict__ out)
{
    const int t  = blockIdx.x * 256 + threadIdx.x;
    const int w2 = t & (W2 - 1);          // lane id: wave spans one row
    const int hb = (t >> 6) & (HBLK - 1); // wave id within block
    const int c  = (t >> 8) & (CC - 1);
    const int b  = t >> 14;

    // Per-channel Haar taps: f[k] = {p0q0, p0q1, p1q0, p1q1}
    const f32x4* f4 = (const f32x4*)(filt + c * 16);
    const f32x4 f0 = f4[0], f1 = f4[1], f2 = f4[2], f3 = f4[3];

    const int plane = HH * WW;            // 16384 floats
    const int h0    = hb * HPB;
    const float* xr = x + ((b * (4 * CC) + c * 4) * HH + h0) * WW + w2 * 2;
    float*       oq = out + ((b * CC + c) * (2 * HH) + 2 * h0) * (2 * WW) + w2 * 4;

#pragma unroll 2
    for (int i = 0; i < HPB; ++i) {
        const f32x2 a0 = __builtin_nontemporal_load((const f32x2*)(xr + 0 * plane));
        const f32x2 a1 = __builtin_nontemporal_load((const f32x2*)(xr + 1 * plane));
        const f32x2 a2 = __builtin_nontemporal_load((const f32x2*)(xr + 2 * plane));
        const f32x2 a3 = __builtin_nontemporal_load((const f32x2*)(xr + 3 * plane));

        f32x4 r0, r1;   // output rows 2h and 2h+1, cols [4*w2, 4*w2+4)
        r0.x = a0.x * f0.x + a1.x * f1.x + a2.x * f2.x + a3.x * f3.x;
        r0.y = a0.x * f0.y + a1.x * f1.y + a2.x * f2.y + a3.x * f3.y;
        r0.z = a0.y * f0.x + a1.y * f1.x + a2.y * f2.x + a3.y * f3.x;
        r0.w = a0.y * f0.y + a1.y * f1.y + a2.y * f2.y + a3.y * f3.y;
        r1.x = a0.x * f0.z + a1.x * f1.z + a2.x * f2.z + a3.x * f3.z;
        r1.y = a0.x * f0.w + a1.x * f1.w + a2.x * f2.w + a3.x * f3.w;
        r1.z = a0.y * f0.z + a1.y * f1.z + a2.y * f2.z + a3.y * f3.z;
        r1.w = a0.y * f0.w + a1.y * f1.w + a2.y * f2.w + a3.y * f3.w;

        __builtin_nontemporal_store(r0, (f32x4*)oq);
        __builtin_nontemporal_store(r1, (f32x4*)(oq + 2 * WW));

        xr += WW;            // next input row (sequential 512B advance)
        oq += 2 * (2 * WW);  // next output row-pair (sequential 2KB advance)
    }
}

extern "C" void kernel_launch(void* const* d_in, const int* in_sizes, int n_in,
                              void* d_out, int out_size, void* d_ws, size_t ws_size,
                              hipStream_t stream) {
    const float* x    = (const float*)d_in[0];
    const float* filt = (const float*)d_in[1];
    float* out        = (float*)d_out;

    const int threads = 256;
    const int blocks  = NTHREADS / threads;   // 1024 blocks = 4 per CU
    ihaar2d_kernel<<<blocks, threads, 0, stream>>>(x, filt, out);
}